// Round 2
// baseline (4442.830 us; speedup 1.0000x reference)
//
#include <hip/hip_runtime.h>

// Problem constants (reference: B=32, S=8192, D=32, C=256)
#define S_LEN 8192
#define BATCH 32
#define DH    32
#define NC    256

typedef float  f32x2 __attribute__((ext_vector_type(2)));
typedef float  f32x4 __attribute__((ext_vector_type(4)));

// sigmoid via native exp + rcp (1-2 ulp; threshold has ~6x margin over this)
__device__ __forceinline__ float sigf(float x) {
    return __builtin_amdgcn_rcpf(1.0f + __expf(-x));
}
__device__ __forceinline__ float rdlane(float v, int l) {
    return __int_as_float(__builtin_amdgcn_readlane(__float_as_int(v), l));
}

// Broadcast helpers across the 64-lane wave using gfx950 v_permlane32_swap_b32
// (pure VALU -- no LDS round trip). permlane32_swap(v,v) returns:
//   r[0][lane] = v[lane & 31]        (lo-half broadcast to both halves)
//   r[1][lane] = v[32 + (lane & 31)] (hi-half broadcast to both halves)
__device__ __forceinline__ float bcast_lo32(float v) {
#if __has_builtin(__builtin_amdgcn_permlane32_swap)
    auto r = __builtin_amdgcn_permlane32_swap(__float_as_uint(v), __float_as_uint(v), false, false);
    return __uint_as_float(r[0]);
#else
    int addr = (int)((threadIdx.x & 31) << 2);
    return __int_as_float(__builtin_amdgcn_ds_bpermute(addr, __float_as_int(v)));
#endif
}
__device__ __forceinline__ float bcast_hi32(float v) {
#if __has_builtin(__builtin_amdgcn_permlane32_swap)
    auto r = __builtin_amdgcn_permlane32_swap(__float_as_uint(v), __float_as_uint(v), false, false);
    return __uint_as_float(r[1]);
#else
    int addr = (int)((32 | (threadIdx.x & 31)) << 2);
    return __int_as_float(__builtin_amdgcn_ds_bpermute(addr, __float_as_int(v)));
#endif
}

// One wave per batch. Lane j owns gate columns k1=j (i for j<32, f for j>=32)
// and k2=j+64 (g for j<32, o for j>=32). h is broadcast each step through a
// 32-float LDS buffer read back as uniform-address float4s, feeding packed
// (v_pk_fma_f32) dot products over d-pairs.
__global__ __launch_bounds__(64, 1) void lstm_scan_kernel(
    const float* __restrict__ x,      // (B,S)
    const float* __restrict__ bos,    // (D)
    const float* __restrict__ W_in,   // (1,D)
    const float* __restrict__ b_in,   // (D)
    const float* __restrict__ Wx,     // (D,4D)
    const float* __restrict__ Wh,     // (D,4D)
    const float* __restrict__ b_lstm, // (4D)
    float* __restrict__ hs)           // (B,S,D) workspace
{
    __shared__ float hlds[64];        // [0..31] = h, [32..63] = duplicate sink

    const int b    = blockIdx.x;
    const int lane = threadIdx.x;     // 0..63
    const int col  = lane & 31;
    const int k1   = lane;
    const int k2   = lane + 64;
    const bool lo  = lane < 32;

    // Recurrent weight columns, packed over d-pairs: wh1[p] = (Wh[2p][k1], Wh[2p+1][k1])
    f32x2 wh1[16], wh2[16];
#pragma unroll
    for (int p = 0; p < 16; ++p) {
        wh1[p] = f32x2{Wh[(2 * p) * 4 * DH + k1], Wh[(2 * p + 1) * 4 * DH + k1]};
        wh2[p] = f32x2{Wh[(2 * p) * 4 * DH + k2], Wh[(2 * p + 1) * 4 * DH + k2]};
    }

    // Rank-1 input projection: zx[t,k] = x[t-1]*v_k + u_k (t>=1); zx[0,k] = z0_k
    float u1 = b_lstm[k1], u2 = b_lstm[k2];
    float z01 = u1, z02 = u2;         // bos @ Wx + b_lstm (bos is used raw)
    float v1 = 0.f, v2 = 0.f;
#pragma unroll
    for (int d = 0; d < DH; ++d) {
        const float wx1 = Wx[d * 4 * DH + k1];
        const float wx2 = Wx[d * 4 * DH + k2];
        const float wi = W_in[d];
        v1 = fmaf(wi, wx1, v1);  v2 = fmaf(wi, wx2, v2);
        const float bi = b_in[d];
        u1 = fmaf(bi, wx1, u1);  u2 = fmaf(bi, wx2, u2);
        const float bd = bos[d];
        z01 = fmaf(bd, wx1, z01); z02 = fmaf(bd, wx2, z02);
    }

    // Branchless nonlinearity constants: s1 = sigmoid(z1) always (i|f);
    // s2 = tanh(z2) for lo (g), sigmoid(z2) for hi (o); tanh(x)=2*sig(2x)-1.
    const float m2 = lo ? 2.f : 1.f;
    const float aa = lo ? 2.f : 1.f;
    const float bb = lo ? -1.f : 0.f;

    const float* xb  = x  + (size_t)b * S_LEN;
    float*       hsb = hs + (size_t)b * S_LEN * DH;

    float c = 0.f;
    *(volatile float*)(hlds + lane) = 0.f;   // h_{-1} = 0 (and dummy sink)

    // x chunk in registers: lane holds x[t-1] for t = chunk*64 + lane
    float xc;
    {
        const int xi = lane - 1;
        xc = (xi >= 0) ? xb[xi] : 0.f;
    }

    for (int chunk = 0; chunk < S_LEN / 64; ++chunk) {
        float xn = 0.f;
        if (chunk + 1 < S_LEN / 64) xn = xb[(chunk + 1) * 64 - 1 + lane];

        for (int i = 0; i < 64; ++i) {
            const float xs = rdlane(xc, i);

            // Broadcast h_{t-1} from LDS as uniform-address float4 reads
            // (volatile: pins program order after last iteration's ds_write;
            //  per-wave DS pipe is in-order, so data is correct without fence).
            const f32x4 q0 = *(volatile const f32x4*)(hlds + 0);
            const f32x4 q1 = *(volatile const f32x4*)(hlds + 4);
            const f32x4 q2 = *(volatile const f32x4*)(hlds + 8);
            const f32x4 q3 = *(volatile const f32x4*)(hlds + 12);
            const f32x4 q4 = *(volatile const f32x4*)(hlds + 16);
            const f32x4 q5 = *(volatile const f32x4*)(hlds + 20);
            const f32x4 q6 = *(volatile const f32x4*)(hlds + 24);
            const f32x4 q7 = *(volatile const f32x4*)(hlds + 28);

            // Packed dot products: 4 accumulator chains, 8 pk_fma deep each.
            f32x2 a1 = {fmaf(xs, v1, u1), 0.f}, b1 = {0.f, 0.f};
            f32x2 a2 = {fmaf(xs, v2, u2), 0.f}, b2 = {0.f, 0.f};
            a1 += q0.xy * wh1[0];  b1 += q0.zw * wh1[1];
            a2 += q0.xy * wh2[0];  b2 += q0.zw * wh2[1];
            a1 += q1.xy * wh1[2];  b1 += q1.zw * wh1[3];
            a2 += q1.xy * wh2[2];  b2 += q1.zw * wh2[3];
            a1 += q2.xy * wh1[4];  b1 += q2.zw * wh1[5];
            a2 += q2.xy * wh2[4];  b2 += q2.zw * wh2[5];
            a1 += q3.xy * wh1[6];  b1 += q3.zw * wh1[7];
            a2 += q3.xy * wh2[6];  b2 += q3.zw * wh2[7];
            a1 += q4.xy * wh1[8];  b1 += q4.zw * wh1[9];
            a2 += q4.xy * wh2[8];  b2 += q4.zw * wh2[9];
            a1 += q5.xy * wh1[10]; b1 += q5.zw * wh1[11];
            a2 += q5.xy * wh2[10]; b2 += q5.zw * wh2[11];
            a1 += q6.xy * wh1[12]; b1 += q6.zw * wh1[13];
            a2 += q6.xy * wh2[12]; b2 += q6.zw * wh2[13];
            a1 += q7.xy * wh1[14]; b1 += q7.zw * wh1[15];
            a2 += q7.xy * wh2[14]; b2 += q7.zw * wh2[15];

            const f32x2 r1 = a1 + b1;
            const f32x2 r2 = a2 + b2;
            float z1 = r1.x + r1.y;
            float z2 = r2.x + r2.y;

            // t == 0 uses the BOS-token gate inputs instead (uniform select;
            // also discards the garbage from the uninitialized first read).
            const bool first = (chunk == 0) && (i == 0);
            z1 = first ? z01 : z1;
            z2 = first ? z02 : z2;

            const float s1 = sigf(z1);                        // sig(i) | sig(f)
            const float s2 = fmaf(aa, sigf(m2 * z2), bb);     // tanh(g) | sig(o)
            const float m  = s1 * s2;                         // lo half: sig(i)*tanh(g)

            const float ig = bcast_lo32(m);                   // all lanes
            const float f_ = bcast_hi32(s1);                  // sig(f), all lanes
            const float o_ = bcast_hi32(s2);                  // sig(o), all lanes

            c = fmaf(f_, c, ig);
            const float tc = fmaf(2.f, sigf(2.f * c), -1.f);  // tanh(c)
            const float h  = o_ * tc;

            // Publish h for next step's broadcast (lanes >=32 hit the sink).
            *(volatile float*)(hlds + lane) = h;
            // Duplicate-address store (lane pairs hold bit-identical h).
            hsb[(size_t)(chunk * 64 + i) * DH + col] = h;
        }
        xc = xn;
    }
}

// Projection: logits[b,t,c] = hs[b,t,:] @ W_out[:,c] + b_out[c]
__global__ __launch_bounds__(256, 4) void proj_kernel(
    const float* __restrict__ hs,     // (B,S,D)
    const float* __restrict__ W_out,  // (D,C)
    const float* __restrict__ b_out,  // (C)
    float* __restrict__ out)          // (B,S,C)
{
    __shared__ float hbuf[128 * DH];  // 16 KiB
    const int tid = threadIdx.x;
    const int b   = blockIdx.y;
    const int t0  = blockIdx.x * 128;

    const float4* src4 = (const float4*)(hs + ((size_t)b * S_LEN + t0) * DH);
    float4* dst4 = (float4*)hbuf;
#pragma unroll
    for (int k = 0; k < 4; ++k) dst4[tid + k * 256] = src4[tid + k * 256];
    __syncthreads();

    const int cc = tid;               // output column
    float w[DH];
#pragma unroll
    for (int d = 0; d < DH; ++d) w[d] = W_out[d * NC + cc];
    const float bo = b_out[cc];

    float* dst = out + ((size_t)b * S_LEN + t0) * NC + cc;
    for (int r = 0; r < 128; ++r) {
        float acc = bo;
#pragma unroll
        for (int d = 0; d < DH; ++d) acc = fmaf(hbuf[r * DH + d], w[d], acc);
        dst[(size_t)r * NC] = acc;    // 64 consecutive lanes -> 256B coalesced
    }
}

extern "C" void kernel_launch(void* const* d_in, const int* in_sizes, int n_in,
                              void* d_out, int out_size, void* d_ws, size_t ws_size,
                              hipStream_t stream) {
    const float* x      = (const float*)d_in[0];
    const float* bos    = (const float*)d_in[1];
    const float* W_in   = (const float*)d_in[2];
    const float* b_in   = (const float*)d_in[3];
    const float* Wx     = (const float*)d_in[4];
    const float* Wh     = (const float*)d_in[5];
    const float* b_lstm = (const float*)d_in[6];
    const float* W_out  = (const float*)d_in[7];
    const float* b_out  = (const float*)d_in[8];

    float* out = (float*)d_out;
    float* hs  = (float*)d_ws;   // B*S*D*4 = 33.5 MB of workspace

    lstm_scan_kernel<<<dim3(BATCH), dim3(64), 0, stream>>>(
        x, bos, W_in, b_in, Wx, Wh, b_lstm, hs);
    proj_kernel<<<dim3(S_LEN / 128, BATCH), dim3(256), 0, stream>>>(
        hs, W_out, b_out, out);
}